// Round 2
// baseline (477.752 us; speedup 1.0000x reference)
//
#include <hip/hip_runtime.h>

#define NSTATES 64

typedef float f2 __attribute__((ext_vector_type(2)));

__global__ __launch_bounds__(256) void diag_logmatexp_kernel(
    const float* __restrict__ xx,
    const float* __restrict__ diag,
    float* __restrict__ out,
    int B)
{
    __shared__ float sh_ed[NSTATES];   // exp(diag[i]) - 1
    const int tid = threadIdx.x;
    if (tid < NSTATES) sh_ed[tid] = __expf(diag[tid]) - 1.0f;
    __syncthreads();

    const long long Bp = (long long)B >> 1;              // column pairs
    const long long stride = (long long)gridDim.x * blockDim.x;

    for (long long jp = (long long)blockIdx.x * blockDim.x + tid; jp < Bp; jp += stride) {
        const size_t col = (size_t)jp * 2;
        f2 v[NSTATES];

        // Load 2 columns (8 B/lane, coalesced, nontemporal: read-once stream).
        #pragma unroll
        for (int k = 0; k < NSTATES; ++k)
            v[k] = __builtin_nontemporal_load(
                       (const f2*)(xx + (size_t)k * (size_t)B + col));

        // Per-column max.
        f2 m = v[0];
        #pragma unroll
        for (int k = 1; k < NSTATES; ++k) {
            m.x = fmaxf(m.x, v[k].x);
            m.y = fmaxf(m.y, v[k].y);
        }

        // S = sum_k exp(v-m); overwrite v with exp(v-m).
        f2 S = {0.0f, 0.0f};
        #pragma unroll
        for (int k = 0; k < NSTATES; ++k) {
            float ex = __expf(v[k].x - m.x);
            float ey = __expf(v[k].y - m.y);
            v[k].x = ex; v[k].y = ey;
            S.x += ex; S.y += ey;
        }

        // out[i,j] = m + log(S + e_i * (exp(diag[i]) - 1)); write-once stream.
        #pragma unroll
        for (int i = 0; i < NSTATES; ++i) {
            const float ed = sh_ed[i];
            f2 o;
            o.x = m.x + __logf(S.x + v[i].x * ed);
            o.y = m.y + __logf(S.y + v[i].y * ed);
            __builtin_nontemporal_store(o, (f2*)(out + (size_t)i * (size_t)B + col));
        }
    }

    // Odd-B tail (B is even in this problem; defensive only).
    if ((B & 1) && blockIdx.x == 0 && tid == 0) {
        const size_t j = (size_t)B - 1;
        float w[NSTATES];
        float m = -1e30f;
        for (int k = 0; k < NSTATES; ++k) {
            w[k] = xx[(size_t)k * (size_t)B + j];
            m = fmaxf(m, w[k]);
        }
        float S = 0.0f;
        for (int k = 0; k < NSTATES; ++k) { w[k] = __expf(w[k] - m); S += w[k]; }
        for (int i = 0; i < NSTATES; ++i)
            out[(size_t)i * (size_t)B + j] = m + __logf(S + w[i] * sh_ed[i]);
    }
}

extern "C" void kernel_launch(void* const* d_in, const int* in_sizes, int n_in,
                              void* d_out, int out_size, void* d_ws, size_t ws_size,
                              hipStream_t stream) {
    const float* xx   = (const float*)d_in[0];
    const float* diag = (const float*)d_in[1];
    float* out = (float*)d_out;

    const int B = in_sizes[0] / NSTATES;   // xx is [64, B]

    const int block = 256;
    const long long pairs = ((long long)B >> 1);
    long long want = (pairs + block - 1) / block;
    int grid = 2048;                        // grid-stride; 256 CUs x 8 blocks
    if (want < grid) grid = (int)(want > 0 ? want : 1);

    diag_logmatexp_kernel<<<grid, block, 0, stream>>>(xx, diag, out, B);
}